// Round 3
// baseline (1032.213 us; speedup 1.0000x reference)
//
#include <hip/hip_runtime.h>
#include <hip/hip_bf16.h>

// Problem constants
constexpr int B_ = 32, S_ = 512, D_ = 512, H_ = 8, L_ = 4, F_ = 2048, DK_ = 64;

typedef __attribute__((ext_vector_type(8))) short short8;
typedef __attribute__((ext_vector_type(4))) float f32x4;

__device__ inline unsigned short f2b(float f) {
  union { __hip_bfloat16 h; unsigned short u; } cv;
  cv.h = __float2bfloat16(f);
  return cv.u;
}
__device__ inline float b2f(unsigned short u) {
  union { unsigned int i; float f; } c;
  c.i = ((unsigned int)u) << 16;
  return c.f;
}
__device__ inline float waveReduceSum(float v) {
  #pragma unroll
  for (int o = 32; o > 0; o >>= 1) v += __shfl_xor(v, o);
  return v;
}

// ---------------- prep: x = q + pos (f32 + bf16), y = qa + pos (bf16) --------
__global__ void prep_kernel(const float4* __restrict__ q, const float4* __restrict__ qa,
                            const float4* __restrict__ pos, float4* __restrict__ xf,
                            uint2* __restrict__ xb, uint2* __restrict__ yb) {
  int i = blockIdx.x * blockDim.x + threadIdx.x;  // 2,097,152 exact
  float4 p = pos[i & 65535];
  float4 a = q[i], c = qa[i];
  float4 xv, yv;
  xv.x = a.x + p.x; xv.y = a.y + p.y; xv.z = a.z + p.z; xv.w = a.w + p.w;
  yv.x = c.x + p.x; yv.y = c.y + p.y; yv.z = c.z + p.z; yv.w = c.w + p.w;
  xf[i] = xv;
  uint2 px, py;
  px.x = (unsigned)f2b(xv.x) | ((unsigned)f2b(xv.y) << 16);
  px.y = (unsigned)f2b(xv.z) | ((unsigned)f2b(xv.w) << 16);
  py.x = (unsigned)f2b(yv.x) | ((unsigned)f2b(yv.y) << 16);
  py.y = (unsigned)f2b(yv.z) | ((unsigned)f2b(yv.w) << 16);
  xb[i] = px;
  yb[i] = py;
}

// ---------------- cast fp32 -> bf16 ------------------------------------------
__global__ void cast_kernel(const float4* __restrict__ src, uint2* __restrict__ dst, int n4) {
  int i = blockIdx.x * blockDim.x + threadIdx.x;
  if (i >= n4) return;
  float4 v = src[i];
  uint2 p;
  p.x = (unsigned)f2b(v.x) | ((unsigned)f2b(v.y) << 16);
  p.y = (unsigned)f2b(v.z) | ((unsigned)f2b(v.w) << 16);
  dst[i] = p;
}

// ---------------- 256-col MFMA GEMM, stage-ahead double-buffered -------------
// C[M,N] = A[M,K] @ W[N,K]^T (+bias on z==0). BN=256, BK=64, 8 waves (2Mx4N).
// Tile k+1 staged (global_load_lds, chunk^(row&7) swizzle) while tile k
// computes; one vmcnt(0)+barrier per K-tile.
// STORE: 0 = bf16, 1 = f32 (z selects Cf/Cf2 for split-K partials), 2 = per-
// head transposed bf16 vT[((b*8+h)*64+d)*512 + t].
template<int BM, int RELU, int STORE>
__global__ __launch_bounds__(512, 2) void gemm256_kernel(
    const __hip_bfloat16* __restrict__ A,
    const __hip_bfloat16* __restrict__ W,
    const float* __restrict__ bias,
    float* __restrict__ Cf, float* __restrict__ Cf2,
    __hip_bfloat16* __restrict__ Cb,
    int Ndim, int Kdim, int kLen)
{
  constexpr int ABUF = BM * 128;   // bytes per A LDS buffer (BM x 64 bf16)
  constexpr int BBASE = 2 * ABUF;
  constexpr int M_REP = BM / 32;
  __shared__ char lds[BBASE + 65536];
  const int tid = threadIdx.x, wave = tid >> 6, lane = tid & 63;
  const int rl = lane & 15, gq = lane >> 4;
  const int wr = wave >> 2, wc = wave & 3;
  const int row0 = blockIdx.y * BM;
  const int col0 = blockIdx.x * 256;
  const int kOff = blockIdx.z * kLen;

  f32x4 acc[M_REP][4] = {};
  const int ntiles = kLen >> 6;

  auto stage = [&](int kt, int d) {
    const int kbase = kOff + (kt << 6);
    #pragma unroll
    for (int r = 0; r < BM / 64; ++r) {
      int p = r * 8192 + wave * 1024 + lane * 16;
      int R = p >> 7, q = (p >> 4) & 7;
      int gc = q ^ (R & 7);
      const __hip_bfloat16* src = A + (size_t)(row0 + R) * Kdim + kbase + gc * 8;
      __builtin_amdgcn_global_load_lds(
          (const __attribute__((address_space(1))) void*)src,
          (__attribute__((address_space(3))) void*)(lds + d * ABUF + p), 16, 0, 0);
    }
    #pragma unroll
    for (int r = 0; r < 4; ++r) {
      int p = r * 8192 + wave * 1024 + lane * 16;
      int R = p >> 7, q = (p >> 4) & 7;
      int gc = q ^ (R & 7);
      const __hip_bfloat16* src = W + (size_t)(col0 + R) * Kdim + kbase + gc * 8;
      __builtin_amdgcn_global_load_lds(
          (const __attribute__((address_space(1))) void*)src,
          (__attribute__((address_space(3))) void*)(lds + BBASE + d * 32768 + p), 16, 0, 0);
    }
  };

  stage(0, 0);
  for (int kt = 0; kt < ntiles; ++kt) {
    const int d = kt & 1;
    // buf d's loads were issued one full tile ago; nothing newer outstanding.
    asm volatile("s_waitcnt vmcnt(0)" ::: "memory");
    __builtin_amdgcn_sched_barrier(0);
    __syncthreads();
    // stage next tile into d^1 (tile kt-1's buffer: all waves are past its
    // compute thanks to the barrier above).
    if (kt + 1 < ntiles) stage(kt + 1, d ^ 1);
    __builtin_amdgcn_sched_barrier(0);

    #pragma unroll
    for (int ph = 0; ph < 4; ++ph) {
      constexpr int MH = M_REP / 2;
      const int mh = ph >> 1, nh = ph & 1;
      short8 aF[MH][2], bF[2][2];
      #pragma unroll
      for (int mi = 0; mi < MH; ++mi) {
        int r = wr * (BM / 2) + (mh * MH + mi) * 16 + rl;
        #pragma unroll
        for (int kf = 0; kf < 2; ++kf)
          aF[mi][kf] = *(const short8*)(lds + d * ABUF + r * 128 +
                                        (((kf * 4 + gq) ^ (r & 7)) << 4));
      }
      #pragma unroll
      for (int ni = 0; ni < 2; ++ni) {
        int r = wc * 64 + (nh * 2 + ni) * 16 + rl;
        #pragma unroll
        for (int kf = 0; kf < 2; ++kf)
          bF[ni][kf] = *(const short8*)(lds + BBASE + d * 32768 + r * 128 +
                                        (((kf * 4 + gq) ^ (r & 7)) << 4));
      }
      __builtin_amdgcn_s_setprio(1);
      #pragma unroll
      for (int mi = 0; mi < MH; ++mi)
        #pragma unroll
        for (int ni = 0; ni < 2; ++ni)
          #pragma unroll
          for (int kf = 0; kf < 2; ++kf)
            acc[mh * MH + mi][nh * 2 + ni] = __builtin_amdgcn_mfma_f32_16x16x32_bf16(
                aF[mi][kf], bF[ni][kf], acc[mh * MH + mi][nh * 2 + ni], 0, 0, 0);
      __builtin_amdgcn_s_setprio(0);
    }
  }

  // epilogue: frag row = gq*4+j, col = rl
  const bool addb = (bias != nullptr) && (blockIdx.z == 0);
  float* cfd = blockIdx.z ? Cf2 : Cf;
  #pragma unroll
  for (int n = 0; n < 4; ++n) {
    int col = col0 + wc * 64 + n * 16 + rl;
    float bv = addb ? bias[col] : 0.0f;
    #pragma unroll
    for (int m = 0; m < M_REP; ++m) {
      #pragma unroll
      for (int j = 0; j < 4; ++j) {
        int row = row0 + wr * (BM / 2) + m * 16 + gq * 4 + j;
        float val = acc[m][n][j] + bv;
        if (RELU) val = fmaxf(val, 0.0f);
        if (STORE == 1) {
          cfd[(size_t)row * Ndim + col] = val;
        } else if (STORE == 0) {
          union { __hip_bfloat16 h; unsigned short u; } cv;
          cv.u = f2b(val);
          Cb[(size_t)row * Ndim + col] = cv.h;
        } else {
          size_t off = (((size_t)((row >> 9) * 8 + (col >> 6)) * 64 + (col & 63)) << 9) + (row & 511);
          union { __hip_bfloat16 h; unsigned short u; } cv;
          cv.u = f2b(val);
          Cb[off] = cv.h;
        }
      }
    }
  }
}

// ---------------- flash attention (MFMA, strict-causal, fr-scaled) -----------
// grid (S/128, B*H), 4 waves; wave owns 32 q-rows. K/V tiles of 64 double-
// buffered in LDS (stage t+1 before compute t, vmcnt(4)); V pre-transposed.
__global__ __launch_bounds__(256, 2) void fattn_kernel(
    const __hip_bfloat16* __restrict__ kq,  // [B*S, D]
    const __hip_bfloat16* __restrict__ vT,  // [(b*8+h)*64+d][t]
    const float* __restrict__ fr,           // [B*S]
    __hip_bfloat16* __restrict__ ctx)       // [B*S, D]
{
  __shared__ char lds[40960];  // K0 K1 [0,16K), V0 V1 [16K,32K), P [32K,40K)
  const int tid = threadIdx.x, wave = tid >> 6, lane = tid & 63;
  const int rl = lane & 15, gq = lane >> 4;
  const int qb = blockIdx.x * 128;
  const int bh = blockIdx.y;
  const int b = bh >> 3, h = bh & 7;
  const size_t kqbase = ((size_t)b * S_) * D_ + h * DK_;
  const size_t vtbase = ((size_t)bh * DK_) * S_;
  const int qw0 = qb + wave * 32;
  const int qw_end = qw0 + 32;

  short8 qA[2][2];
  #pragma unroll
  for (int qf = 0; qf < 2; ++qf)
    #pragma unroll
    for (int kf = 0; kf < 2; ++kf)
      qA[qf][kf] = *(const short8*)(kq + kqbase + (size_t)(qw0 + qf * 16 + rl) * D_ + kf * 32 + gq * 8);

  float sfv[2][4];
  #pragma unroll
  for (int qf = 0; qf < 2; ++qf)
    #pragma unroll
    for (int j = 0; j < 4; ++j)
      sfv[qf][j] = fr[b * S_ + qw0 + qf * 16 + gq * 4 + j] * 0.125f;

  f32x4 o[2][4] = {};
  float mrow[2][4], lrow[2][4];
  #pragma unroll
  for (int qf = 0; qf < 2; ++qf)
    #pragma unroll
    for (int j = 0; j < 4; ++j) { mrow[qf][j] = -3.0e38f; lrow[qf][j] = 0.0f; }

  int sgoff[2], sldsoff[2];
  #pragma unroll
  for (int c = 0; c < 2; ++c) {
    int p = (wave * 2 + c) * 1024 + lane * 16;
    int r = p >> 7;
    int ch = (p >> 4) & 7;
    sgoff[c] = r * 1024 + ((ch ^ (r & 7)) << 4);
    sldsoff[c] = (wave * 2 + c) * 1024;
  }
  const char* kgbase = (const char*)kq + kqbase * 2;
  const char* vgbase = (const char*)vT + vtbase * 2;

  auto stage = [&](int ti, int d) {
    const int t0 = ti << 6;
    #pragma unroll
    for (int c = 0; c < 2; ++c) {
      __builtin_amdgcn_global_load_lds(
          (const __attribute__((address_space(1))) void*)(kgbase + (size_t)t0 * 1024 + sgoff[c]),
          (__attribute__((address_space(3))) void*)(lds + d * 8192 + sldsoff[c]), 16, 0, 0);
      __builtin_amdgcn_global_load_lds(
          (const __attribute__((address_space(1))) void*)(vgbase + t0 * 2 + sgoff[c]),
          (__attribute__((address_space(3))) void*)(lds + 16384 + d * 8192 + sldsoff[c]), 16, 0, 0);
    }
  };

  const int nt = (qb + 128) >> 6;
  stage(0, 0);
  for (int ti = 0; ti < nt; ++ti) {
    const int t0 = ti << 6;
    const int d = ti & 1;
    if (ti + 1 < nt) {
      stage(ti + 1, d ^ 1);
      asm volatile("s_waitcnt vmcnt(4)" ::: "memory");  // drain buf d, keep new 4
    } else {
      asm volatile("s_waitcnt vmcnt(0)" ::: "memory");
    }
    __builtin_amdgcn_sched_barrier(0);
    __syncthreads();

    if (t0 < qw_end) {
      short8 kB[4][2];
      #pragma unroll
      for (int tf = 0; tf < 4; ++tf)
        #pragma unroll
        for (int kf = 0; kf < 2; ++kf) {
          int r = tf * 16 + rl;
          kB[tf][kf] = *(const short8*)(lds + d * 8192 + r * 128 + (((kf * 4 + gq) ^ (r & 7)) << 4));
        }
      short8 vB[4][2];
      #pragma unroll
      for (int df = 0; df < 4; ++df)
        #pragma unroll
        for (int kf = 0; kf < 2; ++kf) {
          int r = df * 16 + rl;
          vB[df][kf] = *(const short8*)(lds + 16384 + d * 8192 + r * 128 + (((kf * 4 + gq) ^ (r & 7)) << 4));
        }

      #pragma unroll
      for (int qf = 0; qf < 2; ++qf) {
        f32x4 c4[4] = {};
        #pragma unroll
        for (int tf = 0; tf < 4; ++tf)
          #pragma unroll
          for (int kf = 0; kf < 2; ++kf)
            c4[tf] = __builtin_amdgcn_mfma_f32_16x16x32_bf16(qA[qf][kf], kB[tf][kf], c4[tf], 0, 0, 0);

        const int qg0 = qw0 + qf * 16 + gq * 4;
        #pragma unroll
        for (int tf = 0; tf < 4; ++tf) {
          int tg = t0 + tf * 16 + rl;
          #pragma unroll
          for (int j = 0; j < 4; ++j) {
            float s = c4[tf][j] * sfv[qf][j];
            c4[tf][j] = (tg >= qg0 + j) ? -3.0e38f : s;
          }
        }
        float tm[4];
        #pragma unroll
        for (int j = 0; j < 4; ++j) {
          tm[j] = fmaxf(fmaxf(c4[0][j], c4[1][j]), fmaxf(c4[2][j], c4[3][j]));
          #pragma unroll
          for (int msk = 1; msk < 16; msk <<= 1) tm[j] = fmaxf(tm[j], __shfl_xor(tm[j], msk));
        }
        #pragma unroll
        for (int j = 0; j < 4; ++j) {
          float mn = fmaxf(mrow[qf][j], tm[j]);
          float fac = __expf(mrow[qf][j] - mn);
          mrow[qf][j] = mn;
          lrow[qf][j] *= fac;
          #pragma unroll
          for (int df = 0; df < 4; ++df) o[qf][df][j] *= fac;
        }
        float rs[4] = {0.f, 0.f, 0.f, 0.f};
        #pragma unroll
        for (int tf = 0; tf < 4; ++tf) {
          int tloc = tf * 16 + rl;
          #pragma unroll
          for (int j = 0; j < 4; ++j) {
            float e = __expf(c4[tf][j] - mrow[qf][j]);
            rs[j] += e;
            int qloc = gq * 4 + j;
            int addr = 32768 + wave * 2048 + qloc * 128 +
                       ((((tloc >> 3) ^ (qloc & 7)) << 4)) + (tloc & 7) * 2;
            *(unsigned short*)(lds + addr) = f2b(e);
          }
        }
        #pragma unroll
        for (int j = 0; j < 4; ++j) {
          float r = rs[j];
          #pragma unroll
          for (int msk = 1; msk < 16; msk <<= 1) r += __shfl_xor(r, msk);
          lrow[qf][j] += r;
        }
        asm volatile("s_waitcnt lgkmcnt(0)" ::: "memory");
        __builtin_amdgcn_sched_barrier(0);
        short8 pA[2];
        #pragma unroll
        for (int kf = 0; kf < 2; ++kf)
          pA[kf] = *(const short8*)(lds + 32768 + wave * 2048 + rl * 128 +
                                    (((kf * 4 + gq) ^ (rl & 7)) << 4));
        #pragma unroll
        for (int df = 0; df < 4; ++df)
          #pragma unroll
          for (int kf = 0; kf < 2; ++kf)
            o[qf][df] = __builtin_amdgcn_mfma_f32_16x16x32_bf16(pA[kf], vB[df][kf], o[qf][df], 0, 0, 0);
      }
    }
    __syncthreads();  // before next iteration's stage overwrites buf d^1
  }

  #pragma unroll
  for (int qf = 0; qf < 2; ++qf)
    #pragma unroll
    for (int j = 0; j < 4; ++j) {
      int qg = qw0 + qf * 16 + gq * 4 + j;
      float inv = (qg == 0) ? 0.0f : 1.0f / lrow[qf][j];
      #pragma unroll
      for (int df = 0; df < 4; ++df) {
        union { __hip_bfloat16 hh; unsigned short u; } cv;
        cv.u = f2b(o[qf][df][j] * inv);
        ctx[((size_t)(b * S_ + qg)) * D_ + h * DK_ + df * 16 + rl] = cv.hh;
      }
    }
}

// ---------------- fused residual + LayerNorm (wave per row) ------------------
// NADD==2 additionally sums add2 (split-K partial combine).
template<int NADD>
__global__ __launch_bounds__(256) void ln_kernel(
    const float4* __restrict__ xin, const float4* __restrict__ add,
    const float4* __restrict__ add2,
    const float* __restrict__ g, const float* __restrict__ bta,
    float4* xf_out, uint2* __restrict__ xb_out)
{
  const int lane = threadIdx.x & 63, wv = threadIdx.x >> 6;
  const size_t row = (size_t)blockIdx.x * 4 + wv;
  const size_t base4 = row * 128;

  float4 x0 = xin[base4 + lane * 2], x1 = xin[base4 + lane * 2 + 1];
  float4 a0 = add[base4 + lane * 2], a1 = add[base4 + lane * 2 + 1];
  float v[8];
  v[0] = x0.x + a0.x; v[1] = x0.y + a0.y; v[2] = x0.z + a0.z; v[3] = x0.w + a0.w;
  v[4] = x1.x + a1.x; v[5] = x1.y + a1.y; v[6] = x1.z + a1.z; v[7] = x1.w + a1.w;
  if (NADD == 2) {
    float4 c0 = add2[base4 + lane * 2], c1 = add2[base4 + lane * 2 + 1];
    v[0] += c0.x; v[1] += c0.y; v[2] += c0.z; v[3] += c0.w;
    v[4] += c1.x; v[5] += c1.y; v[6] += c1.z; v[7] += c1.w;
  }
  float s = 0.0f;
  #pragma unroll
  for (int i = 0; i < 8; ++i) s += v[i];
  s = waveReduceSum(s);
  float mu = s * (1.0f / 512.0f);
  float vs = 0.0f;
  #pragma unroll
  for (int i = 0; i < 8; ++i) { float d = v[i] - mu; vs += d * d; }
  vs = waveReduceSum(vs);
  float rstd = rsqrtf(vs * (1.0f / 512.0f) + 1e-5f);

  const int c0i = lane * 8;
  float4 gg0 = *(const float4*)(g + c0i), gg1 = *(const float4*)(g + c0i + 4);
  float4 bb0 = *(const float4*)(bta + c0i), bb1 = *(const float4*)(bta + c0i + 4);
  float o[8];
  o[0] = (v[0] - mu) * rstd * gg0.x + bb0.x;
  o[1] = (v[1] - mu) * rstd * gg0.y + bb0.y;
  o[2] = (v[2] - mu) * rstd * gg0.z + bb0.z;
  o[3] = (v[3] - mu) * rstd * gg0.w + bb0.w;
  o[4] = (v[4] - mu) * rstd * gg1.x + bb1.x;
  o[5] = (v[5] - mu) * rstd * gg1.y + bb1.y;
  o[6] = (v[6] - mu) * rstd * gg1.z + bb1.z;
  o[7] = (v[7] - mu) * rstd * gg1.w + bb1.w;
  float4 w0, w1;
  w0.x = o[0]; w0.y = o[1]; w0.z = o[2]; w0.w = o[3];
  w1.x = o[4]; w1.y = o[5]; w1.z = o[6]; w1.w = o[7];
  xf_out[base4 + lane * 2] = w0;
  xf_out[base4 + lane * 2 + 1] = w1;
  uint2 p0, p1;
  p0.x = (unsigned)f2b(o[0]) | ((unsigned)f2b(o[1]) << 16);
  p0.y = (unsigned)f2b(o[2]) | ((unsigned)f2b(o[3]) << 16);
  p1.x = (unsigned)f2b(o[4]) | ((unsigned)f2b(o[5]) << 16);
  p1.y = (unsigned)f2b(o[6]) | ((unsigned)f2b(o[7]) << 16);
  xb_out[row * 128 + lane * 2] = p0;
  xb_out[row * 128 + lane * 2 + 1] = p1;
}

// ---------------- launcher ---------------------------------------------------
extern "C" void kernel_launch(void* const* d_in, const int* in_sizes, int n_in,
                              void* d_out, int out_size, void* d_ws, size_t ws_size,
                              hipStream_t stream) {
  (void)in_sizes; (void)n_in; (void)out_size; (void)ws_size;
  const float* q   = (const float*)d_in[0];
  const float* qa  = (const float*)d_in[1];
  const float* frr = (const float*)d_in[2];
  const float* pos = (const float*)d_in[3];
  const float* Wk  = (const float*)d_in[4];
  const float* bk  = (const float*)d_in[5];
  const float* Wv  = (const float*)d_in[6];
  const float* bv  = (const float*)d_in[7];
  const float* Wo  = (const float*)d_in[8];
  const float* bo  = (const float*)d_in[9];
  const float* W1  = (const float*)d_in[10];
  const float* b1  = (const float*)d_in[11];
  const float* W2  = (const float*)d_in[12];
  const float* b2  = (const float*)d_in[13];
  const float* g1  = (const float*)d_in[14];
  const float* be1 = (const float*)d_in[15];
  const float* g2  = (const float*)d_in[16];
  const float* be2 = (const float*)d_in[17];

  char* ws = (char*)d_ws;
  float*          xf   = (float*)(ws + 0);                      // 33.5 MB
  __hip_bfloat16* xb   = (__hip_bfloat16*)(ws + 33554432);
  __hip_bfloat16* yb   = (__hip_bfloat16*)(ws + 50331648);
  __hip_bfloat16* kqb  = (__hip_bfloat16*)(ws + 67108864);
  __hip_bfloat16* vtb  = (__hip_bfloat16*)(ws + 83886080);
  __hip_bfloat16* ctxb = (__hip_bfloat16*)(ws + 100663296);
  __hip_bfloat16* hb   = (__hip_bfloat16*)(ws + 117440512);     // 67.1 MB
  __hip_bfloat16* wkb  = (__hip_bfloat16*)(ws + 184549376);
  __hip_bfloat16* wvb  = (__hip_bfloat16*)(ws + 186646528);
  __hip_bfloat16* wob  = (__hip_bfloat16*)(ws + 188743680);
  __hip_bfloat16* w1b  = (__hip_bfloat16*)(ws + 190840832);
  __hip_bfloat16* w2b  = (__hip_bfloat16*)(ws + 199229440);
  float* pf1  = (float*)(ws + 67108864);   // FFN2 split-K partial 1 (over kqb+vtb, dead then)
  float* outf = (float*)d_out;             // fp32 scratch / FFN2 partial 0

  prep_kernel<<<8192, 256, 0, stream>>>((const float4*)q, (const float4*)qa,
                                        (const float4*)pos, (float4*)xf,
                                        (uint2*)xb, (uint2*)yb);
  cast_kernel<<<1024, 256, 0, stream>>>((const float4*)Wk, (uint2*)wkb, 262144);
  cast_kernel<<<1024, 256, 0, stream>>>((const float4*)Wv, (uint2*)wvb, 262144);
  cast_kernel<<<1024, 256, 0, stream>>>((const float4*)Wo, (uint2*)wob, 262144);
  cast_kernel<<<4096, 256, 0, stream>>>((const float4*)W1, (uint2*)w1b, 1048576);
  cast_kernel<<<4096, 256, 0, stream>>>((const float4*)W2, (uint2*)w2b, 1048576);

  for (int l = 0; l < L_; ++l) {
    gemm256_kernel<128,0,0><<<dim3(2, 128, 1), 512, 0, stream>>>(
        xb, wkb + (size_t)l * 262144, bk + l * 512, nullptr, nullptr, kqb, 512, 512, 512);
    gemm256_kernel<128,0,2><<<dim3(2, 128, 1), 512, 0, stream>>>(
        yb, wvb + (size_t)l * 262144, bv + l * 512, nullptr, nullptr, vtb, 512, 512, 512);
    fattn_kernel<<<dim3(4, 256), 256, 0, stream>>>(kqb, vtb, frr, ctxb);
    gemm256_kernel<128,0,1><<<dim3(2, 128, 1), 512, 0, stream>>>(
        ctxb, wob + (size_t)l * 262144, bo + l * 512, outf, nullptr, nullptr, 512, 512, 512);
    ln_kernel<1><<<4096, 256, 0, stream>>>((const float4*)xf, (const float4*)outf, nullptr,
                                           g1 + l * 512, be1 + l * 512,
                                           (float4*)xf, (uint2*)xb);
    gemm256_kernel<256,1,0><<<dim3(8, 64, 1), 512, 0, stream>>>(
        xb, w1b + (size_t)l * 1048576, b1 + l * 2048, nullptr, nullptr, hb, 2048, 512, 512);
    gemm256_kernel<256,0,1><<<dim3(2, 64, 2), 512, 0, stream>>>(
        hb, w2b + (size_t)l * 1048576, b2 + l * 512, outf, pf1, nullptr, 512, 2048, 1024);
    float* lnout = (l == L_ - 1) ? (float*)d_out : xf;
    ln_kernel<2><<<4096, 256, 0, stream>>>((const float4*)xf, (const float4*)outf,
                                           (const float4*)pf1,
                                           g2 + l * 512, be2 + l * 512,
                                           (float4*)lnout, (uint2*)xb);
  }
}